// Round 3
// baseline (288.959 us; speedup 1.0000x reference)
//
#include <hip/hip_runtime.h>
#include <cstdint>
#include <cstddef>

#define DEV static __device__ __forceinline__

typedef __attribute__((ext_vector_type(8))) short bf16x8;   // 8 bf16 (4 VGPRs)
typedef __attribute__((ext_vector_type(4))) float f32x4;

constexpr int NB   = 64;     // batch
constexpr int NTOK = 197;    // tokens
constexpr int DIMC = 768;    // channels
constexpr int NH   = 12;     // heads
constexpr int HDIM = 64;     // head dim
constexpr int MTOK = NB * NTOK;   // 12608 rows
constexpr int QKVO = 3 * DIMC;    // 2304
constexpr int BH   = NB * NH;     // 768
constexpr int NPAD = 224;         // padded key count (7 x 32)

DEV unsigned short f2bf(float f) {
  union { float f; uint32_t u; } v; v.f = f;
  uint32_t u = v.u;
  return (unsigned short)((u + 0x7FFFu + ((u >> 16) & 1u)) >> 16);  // RNE, finite inputs
}

DEV uint32_t pack_bf2(float a, float b) {
  return (uint32_t)f2bf(a) | ((uint32_t)f2bf(b) << 16);
}

DEV f32x4 mfma16(bf16x8 a, bf16x8 b, f32x4 c) {
  return __builtin_amdgcn_mfma_f32_16x16x32_bf16(a, b, c, 0, 0, 0);
}

DEV void async_cp16(const unsigned short* g, unsigned short* l) {
  // direct global->LDS DMA, 16B/lane; LDS dest is lane-contiguous (no pad!)
  __builtin_amdgcn_global_load_lds(
      (__attribute__((address_space(1))) void*)g,
      (__attribute__((address_space(3))) void*)l, 16, 0, 0);
}

// supertile swizzle: groups of 8 M-tiles, N-major inside the group, so
// consecutive blocks (round-robin over XCDs) share a 1.5MB A-band + full B.
DEV void swizzle_mn(int lin, int gridM, int gridN, int& mbase, int& nbase) {
  int per = 8 * gridN;
  int sup = lin / per;
  int bm  = sup * 8;
  int Gm  = gridM - bm; if (Gm > 8) Gm = 8;
  int rem = lin - sup * per;
  int n   = rem / Gm;
  int mm  = rem - n * Gm;
  mbase = (bm + mm) * 128;
  nbase = n * 128;
}

// ---------------- f32 -> bf16 convert (memory-bound) ----------------
__global__ void __launch_bounds__(256) cvt_bf16(const float* __restrict__ s,
                                                unsigned short* __restrict__ d, int n) {
  int i = (blockIdx.x * 256 + threadIdx.x) * 4;
  if (i < n) {
    float4 f = *(const float4*)(s + i);
    ushort4 o;
    o.x = f2bf(f.x); o.y = f2bf(f.y); o.z = f2bf(f.z); o.w = f2bf(f.w);
    *(ushort4*)(d + i) = o;
  }
}

// ---------------- shared NT-GEMM main loop (m97 structure) ----------------
DEV void gemm_mainloop(const unsigned short* __restrict__ A, int Arows,
                       const unsigned short* __restrict__ Bw,
                       unsigned short* As, unsigned short* Bs,
                       int mbase, int nbase, f32x4 acc[4][4]) {
  const int tid  = threadIdx.x;
  const int lane = tid & 63;
  const int wave = tid >> 6;
  const int wm = wave & 1, wn = wave >> 1;
  const int l16 = lane & 15, quad = lane >> 4;

  for (int k0 = 0; k0 < DIMC; k0 += 64) {
#pragma unroll
    for (int i = 0; i < 4; ++i) {
      int c = i * 256 + tid;          // LDS chunk id 0..1023 (16B chunks)
      int row = c >> 3, cc = c & 7;
      int gc = (cc ^ (row & 7)) * 8;  // swizzled global chunk
      int ar = mbase + row; ar = ar < Arows ? ar : Arows - 1;  // M tail clamp
      async_cp16(A  + (size_t)ar * DIMC + k0 + gc, As + c * 8);
      async_cp16(Bw + (size_t)(nbase + row) * DIMC + k0 + gc, Bs + c * 8);
    }
    __syncthreads();   // compiler drains vmcnt(0) here (covers global_load_lds)
#pragma unroll
    for (int kk = 0; kk < 64; kk += 32) {
      const int cw = (kk >> 3) + quad;
      bf16x8 af[4], bfr[4];
#pragma unroll
      for (int mi = 0; mi < 4; ++mi) {
        int r = wm * 64 + mi * 16 + l16;
        af[mi] = *(const bf16x8*)(As + r * 64 + (cw ^ (r & 7)) * 8);
      }
#pragma unroll
      for (int ni = 0; ni < 4; ++ni) {
        int r = wn * 64 + ni * 16 + l16;
        bfr[ni] = *(const bf16x8*)(Bs + r * 64 + (cw ^ (r & 7)) * 8);
      }
#pragma unroll
      for (int mi = 0; mi < 4; ++mi)
#pragma unroll
        for (int ni = 0; ni < 4; ++ni)
          acc[mi][ni] = mfma16(af[mi], bfr[ni], acc[mi][ni]);
    }
    __syncthreads();
  }
}

// ---------------- QKV GEMM -> Q/K [2][BH][197][64] + V^T [BH][64][224] ----------------
__global__ void __launch_bounds__(256) gemm_qkv(const unsigned short* __restrict__ A,
                                                const unsigned short* __restrict__ Bw,
                                                unsigned short* __restrict__ qkb,
                                                unsigned short* __restrict__ vTb,
                                                int gridM, int gridN) {
  __shared__ __align__(16) unsigned short As[128 * 64];
  __shared__ __align__(16) unsigned short Bs[128 * 64];
  const int tid = threadIdx.x, lane = tid & 63, wave = tid >> 6;
  const int wm = wave & 1, wn = wave >> 1;
  const int l16 = lane & 15, quad = lane >> 4;
  int mbase, nbase;
  swizzle_mn(blockIdx.x, gridM, gridN, mbase, nbase);

  f32x4 acc[4][4];
#pragma unroll
  for (int i = 0; i < 4; ++i)
#pragma unroll
    for (int j = 0; j < 4; ++j) acc[i][j] = {0.f, 0.f, 0.f, 0.f};

  gemm_mainloop(A, MTOK, Bw, As, Bs, mbase, nbase, acc);

  // epilogue: Q,K scatter to [which][b][h][n][hd]; V scatter TRANSPOSED to
  // vT[bh][d][n] (zero extra cost: it's a scalar scatter either way).
  const int oc64  = nbase + wn * 64;            // 64-aligned -> uniform which/h
  const int which = oc64 / DIMC;
  const int h     = (oc64 % DIMC) / HDIM;
#pragma unroll
  for (int mi = 0; mi < 4; ++mi) {
    int t0 = mbase + wm * 64 + mi * 16 + quad * 4;
#pragma unroll
    for (int r = 0; r < 4; ++r) {
      int t = t0 + r;
      if (t < MTOK) {
        int b = t / NTOK, n = t - b * NTOK;
        if (which < 2) {
          size_t base = ((size_t)((which * NB + b) * NH + h) * NTOK + n) * HDIM;
#pragma unroll
          for (int ni = 0; ni < 4; ++ni)
            qkb[base + ni * 16 + l16] = f2bf(acc[mi][ni][r]);
        } else {
          size_t hb = (size_t)(b * NH + h) * HDIM;
#pragma unroll
          for (int ni = 0; ni < 4; ++ni)
            vTb[(hb + ni * 16 + l16) * NPAD + n] = f2bf(acc[mi][ni][r]);
        }
      }
    }
  }
}

// ---------------- Proj GEMM + bias + residual (fp32 out) ----------------
__global__ void __launch_bounds__(256) gemm_proj(const unsigned short* __restrict__ A,
                                                 const unsigned short* __restrict__ Bw,
                                                 const float* __restrict__ bias,
                                                 const float* __restrict__ xres,
                                                 float* __restrict__ out,
                                                 int gridM, int gridN) {
  __shared__ __align__(16) unsigned short As[128 * 64];
  __shared__ __align__(16) unsigned short Bs[128 * 64];
  const int tid = threadIdx.x, lane = tid & 63, wave = tid >> 6;
  const int wm = wave & 1, wn = wave >> 1;
  const int l16 = lane & 15, quad = lane >> 4;
  int mbase, nbase;
  swizzle_mn(blockIdx.x, gridM, gridN, mbase, nbase);

  f32x4 acc[4][4];
#pragma unroll
  for (int i = 0; i < 4; ++i)
#pragma unroll
    for (int j = 0; j < 4; ++j) acc[i][j] = {0.f, 0.f, 0.f, 0.f};

  gemm_mainloop(A, MTOK, Bw, As, Bs, mbase, nbase, acc);

  const int oc = nbase + wn * 64;
#pragma unroll
  for (int mi = 0; mi < 4; ++mi) {
    int t0 = mbase + wm * 64 + mi * 16 + quad * 4;
#pragma unroll
    for (int r = 0; r < 4; ++r) {
      int t = t0 + r;
      if (t < MTOK) {
        size_t rowb = (size_t)t * DIMC;
#pragma unroll
        for (int ni = 0; ni < 4; ++ni) {
          int o = oc + ni * 16 + l16;
          out[rowb + o] = acc[mi][ni][r] + bias[o] + xres[rowb + o];
        }
      }
    }
  }
}

// ---------------- fused attention, one block per (b,h) ----------------
// K staged via global_load_lds (async DMA, XOR-swizzled, conflict-free b128
// reads). V^T read straight from global (pre-transposed by gemm_qkv, L1-hot).
// P C-layout -> B-fragment transpose done with ds_bpermute shuffles: no LDS
// scratch, no barriers, no manual waitcnt anywhere in the loop.
__global__ void __launch_bounds__(256, 2) attn_fused(const unsigned short* __restrict__ qkb,
                                                     const unsigned short* __restrict__ vTb,
                                                     const float* __restrict__ scale,
                                                     unsigned short* __restrict__ aout) {
  __shared__ __align__(16) unsigned short Ks[NPAD * 64];   // 28672 B -> 5 blk/CU by LDS

  const int bh = blockIdx.x;
  const int b = bh / NH, h = bh - b * NH;
  const int tid = threadIdx.x, lane = tid & 63, wave = tid >> 6;
  const int l16 = lane & 15, quad = lane >> 4;

  const unsigned short* qg = qkb + (size_t)bh * (NTOK * HDIM);
  const unsigned short* kg = qkb + (size_t)(BH + bh) * (NTOK * HDIM);
  const unsigned short* vg = vTb + (size_t)bh * (HDIM * NPAD);
  const float sc = scale[h];

  // stage K rows 0..223 (rows >=197 read neighboring valid memory; masked)
#pragma unroll
  for (int i = 0; i < 7; ++i) {
    int c = i * 256 + tid;            // 16B chunk id 0..1791
    int row = c >> 3, cc = c & 7;
    int gc = (cc ^ (row & 7)) * 8;    // swizzled global chunk
    async_cp16(kg + (size_t)row * 64 + gc, Ks + c * 8);
  }
  __syncthreads();

  // P-exchange source lanes (constant per lane)
  const int srcA  = l16 + 16 * ((2 * quad) & 3);
  const int srcB  = l16 + 16 * ((2 * quad + 1) & 3);
  const int stsel = quad >> 1;

  for (int mt = wave; mt < 13; mt += 4) {   // Q 16-row tiles, round-robin
    int qr = mt * 16 + l16; if (qr > NTOK - 1) qr = NTOK - 1;   // clamp tail
    bf16x8 qb0 = *(const bf16x8*)(qg + (size_t)qr * 64 + quad * 8);
    bf16x8 qb1 = *(const bf16x8*)(qg + (size_t)qr * 64 + 32 + quad * 8);
    const int mg = mt * 16 + l16;           // global Q row (for diag mask)

    // ---- batched S^T = K.Q^T: 28 independent MFMAs, K from LDS ----
    f32x4 s[7][2];
#pragma unroll
    for (int jc = 0; jc < 7; ++jc)
#pragma unroll
      for (int st = 0; st < 2; ++st) {
        int jrow = (jc * 2 + st) * 16 + l16;
        const unsigned short* kr = Ks + jrow * 64;
        bf16x8 ka0 = *(const bf16x8*)(kr + (quad       ^ (jrow & 7)) * 8);
        bf16x8 ka1 = *(const bf16x8*)(kr + ((4 + quad) ^ (jrow & 7)) * 8);
        f32x4 t = {0.f, 0.f, 0.f, 0.f};
        t = mfma16(ka0, qb0, t);
        t = mfma16(ka1, qb1, t);
        s[jc][st] = t;
      }

    // ---- single softmax pass: scale + mask, max, exp, sum ----
    float cmax = -1e30f;
#pragma unroll
    for (int jc = 0; jc < 7; ++jc)
#pragma unroll
      for (int st = 0; st < 2; ++st)
#pragma unroll
        for (int r = 0; r < 4; ++r) {
          int jg = jc * 32 + st * 16 + quad * 4 + r;
          float v = s[jc][st][r] * sc;
          v = (jg >= NTOK || jg == mg) ? -1e30f : v;   // select: NaN-safe
          s[jc][st][r] = v;
          cmax = fmaxf(cmax, v);
        }
    cmax = fmaxf(cmax, __shfl_xor(cmax, 16));
    cmax = fmaxf(cmax, __shfl_xor(cmax, 32));
    float psum = 0.f;
#pragma unroll
    for (int jc = 0; jc < 7; ++jc)
#pragma unroll
      for (int st = 0; st < 2; ++st)
#pragma unroll
        for (int r = 0; r < 4; ++r) {
          float e = __expf(s[jc][st][r] - cmax);       // masked -> exp -> +0
          psum += e;
          s[jc][st][r] = e;
        }
    psum += __shfl_xor(psum, 16);
    psum += __shfl_xor(psum, 32);
    const float inv = 1.0f / psum;

    // ---- PV: O^T = V^T . P^T; P^T B-frags assembled via bpermute ----
    f32x4 oacc[4];
#pragma unroll
    for (int dt = 0; dt < 4; ++dt) oacc[dt] = {0.f, 0.f, 0.f, 0.f};

#pragma unroll
    for (int jc = 0; jc < 7; ++jc) {
      uint32_t u0 = pack_bf2(s[jc][0][0], s[jc][0][1]);
      uint32_t v0 = pack_bf2(s[jc][0][2], s[jc][0][3]);
      uint32_t u1 = pack_bf2(s[jc][1][0], s[jc][1][1]);
      uint32_t v1 = pack_bf2(s[jc][1][2], s[jc][1][3]);
      uint32_t au0 = (uint32_t)__shfl((int)u0, srcA);
      uint32_t av0 = (uint32_t)__shfl((int)v0, srcA);
      uint32_t au1 = (uint32_t)__shfl((int)u1, srcA);
      uint32_t av1 = (uint32_t)__shfl((int)v1, srcA);
      uint32_t bu0 = (uint32_t)__shfl((int)u0, srcB);
      uint32_t bv0 = (uint32_t)__shfl((int)v0, srcB);
      uint32_t bu1 = (uint32_t)__shfl((int)u1, srcB);
      uint32_t bv1 = (uint32_t)__shfl((int)v1, srcB);
      union { uint32_t u[4]; bf16x8 v; } pb;
      pb.u[0] = stsel ? au1 : au0;
      pb.u[1] = stsel ? av1 : av0;
      pb.u[2] = stsel ? bu1 : bu0;
      pb.u[3] = stsel ? bv1 : bv0;
#pragma unroll
      for (int dt = 0; dt < 4; ++dt) {
        bf16x8 va = *(const bf16x8*)(vg + (size_t)(dt * 16 + l16) * NPAD +
                                     jc * 32 + quad * 8);   // V^T A-frag, global
        oacc[dt] = mfma16(va, pb.v, oacc[dt]);
      }
    }

    // O^T C-layout: lane holds Q-row l16; d = dt*16 + quad*4 + r
    if (mg < NTOK) {
      size_t ob = (size_t)(b * NTOK + mg) * DIMC + h * HDIM;
#pragma unroll
      for (int dt = 0; dt < 4; ++dt) {
        ushort4 pk;
        pk.x = f2bf(oacc[dt][0] * inv);
        pk.y = f2bf(oacc[dt][1] * inv);
        pk.z = f2bf(oacc[dt][2] * inv);
        pk.w = f2bf(oacc[dt][3] * inv);
        *(ushort4*)(aout + ob + dt * 16 + quad * 4) = pk;
      }
    }
  }
}

// ---------------- launcher ----------------
extern "C" void kernel_launch(void* const* d_in, const int* in_sizes, int n_in,
                              void* d_out, int out_size, void* d_ws, size_t ws_size,
                              hipStream_t stream) {
  const float* x     = (const float*)d_in[0];
  const float* scale = (const float*)d_in[1];
  const float* wqkv  = (const float*)d_in[2];
  const float* wproj = (const float*)d_in[3];
  const float* bproj = (const float*)d_in[4];
  float* out = (float*)d_out;

  // ws layout (ushort elements). attn-out aliases x_bf16 (dead after
  // gemm_qkv; proj residual reads the original fp32 x). Last-head K staging
  // overreads ~3.4KB past qkb into vTb -- valid mapped memory, values masked.
  unsigned short* xb   = (unsigned short*)d_ws;
  unsigned short* wqb  = xb  + (size_t)MTOK * DIMC;             // 9,682,944
  unsigned short* wpb  = wqb + (size_t)QKVO * DIMC;             // 1,769,472
  unsigned short* qkb  = wpb + (size_t)DIMC * DIMC;             //   589,824
  unsigned short* vTb  = qkb + (size_t)2 * BH * NTOK * HDIM;    // 19,365,888
  unsigned short* attb = xb;                                    // alias
  // vTb size: BH*64*224 = 11,010,048 ushorts; total ~84.8 MB

  cvt_bf16<<<(MTOK * DIMC) / 1024, 256, 0, stream>>>(x, xb, MTOK * DIMC);
  cvt_bf16<<<(QKVO * DIMC) / 1024, 256, 0, stream>>>(wqkv, wqb, QKVO * DIMC);
  cvt_bf16<<<(DIMC * DIMC) / 1024, 256, 0, stream>>>(wproj, wpb, DIMC * DIMC);

  const int gmM = (MTOK + 127) / 128;      // 99
  gemm_qkv<<<gmM * (QKVO / 128), 256, 0, stream>>>(xb, wqb, qkb, vTb,
                                                   gmM, QKVO / 128);
  attn_fused<<<BH, 256, 0, stream>>>(qkb, vTb, scale, attb);
  gemm_proj<<<gmM * (DIMC / 128), 256, 0, stream>>>(attb, wpb, bproj, x, out,
                                                    gmM, DIMC / 128);
}